// Round 7
// baseline (405.951 us; speedup 1.0000x reference)
//
#include <hip/hip_runtime.h>
#include <math.h>

#define B_    8
#define C_    256
#define HW_   4096
#define CHW_  ((long)C_ * HW_)

#define BKT   32      // bf16 K per tile
#define LDH   40      // LDS row stride in ushorts (gemm_nt only)
#define KS    16      // split-K for F*G^T
#define KCH   (HW_ / KS)   // 256

typedef __attribute__((ext_vector_type(8))) short bf16x8;
typedef __attribute__((ext_vector_type(4))) float f32x4;
#define MFMA_BF16(a, b, c) __builtin_amdgcn_mfma_f32_16x16x32_bf16((a), (b), (c), 0, 0, 0)

// fp32x4 -> bf16 hi + lo residual, packed 2/dword
__device__ __forceinline__ void cvt_hl4(const float4 f, uint* h, uint* l) {
    uint u0 = __float_as_uint(f.x), u1 = __float_as_uint(f.y),
         u2 = __float_as_uint(f.z), u3 = __float_as_uint(f.w);
    uint h0 = (u0 + 0x8000u) & 0xFFFF0000u, h1 = (u1 + 0x8000u) & 0xFFFF0000u,
         h2 = (u2 + 0x8000u) & 0xFFFF0000u, h3 = (u3 + 0x8000u) & 0xFFFF0000u;
    h[0] = (h0 >> 16) | h1;
    h[1] = (h2 >> 16) | h3;
    float l0 = f.x - __uint_as_float(h0), l1 = f.y - __uint_as_float(h1),
          l2 = f.z - __uint_as_float(h2), l3 = f.w - __uint_as_float(h3);
    uint a0 = __float_as_uint(l0) & 0xFFFF0000u, a1 = __float_as_uint(l1) & 0xFFFF0000u,
         a2 = __float_as_uint(l2) & 0xFFFF0000u, a3 = __float_as_uint(l3) & 0xFFFF0000u;
    l[0] = (a0 >> 16) | a1;
    l[1] = (a2 >> 16) | a3;
}
__device__ __forceinline__ void cvt_h4(const float4 f, uint* h) {
    uint u0 = __float_as_uint(f.x), u1 = __float_as_uint(f.y),
         u2 = __float_as_uint(f.z), u3 = __float_as_uint(f.w);
    uint h0 = (u0 + 0x8000u) & 0xFFFF0000u, h1 = (u1 + 0x8000u) & 0xFFFF0000u,
         h2 = (u2 + 0x8000u) & 0xFFFF0000u, h3 = (u3 + 0x8000u) & 0xFFFF0000u;
    h[0] = (h0 >> 16) | h1;
    h[1] = (h2 >> 16) | h3;
}

// Wv -> bf16 hi copy
__global__ __launch_bounds__(256) void conv_w(
    const float* __restrict__ Wv, ushort* __restrict__ Wvh)
{
    const int i = (blockIdx.x * 256 + threadIdx.x) * 4;
    float4 v = *reinterpret_cast<const float4*>(&Wv[i]);
    uint h[2];
    cvt_h4(v, h);
    *reinterpret_cast<uint2*>(&Wvh[i]) = make_uint2(h[0], h[1]);
}

// ===========================================================================
// Transposed bf16 conversion: mask[b][e][i] -> maskT hi/lo [b][i][e];
// fg -> fgT hi [b][i][e].   64x64 tiles through LDS.
// ===========================================================================
__global__ __launch_bounds__(256) void conv_transpose(
    const float* __restrict__ mask, const float* __restrict__ fg,
    ushort* __restrict__ mTh, ushort* __restrict__ mTl, ushort* __restrict__ fTh)
{
    __shared__ float tile[64][65];
    const int zi = blockIdx.z;
    const bool domask = zi < B_;
    const int b = domask ? zi : zi - B_;
    const float* src = (domask ? mask : fg) + (long)b * CHW_;
    const int e0 = blockIdx.y * 64, i0 = blockIdx.x * 64;

    const int t  = threadIdx.x;
    const int tr = t >> 4, tc = (t & 15) * 4;

    #pragma unroll
    for (int j = 0; j < 4; ++j) {
        const int e = tr + j * 16;
        float4 v = *reinterpret_cast<const float4*>(&src[(long)(e0 + e) * HW_ + i0 + tc]);
        tile[e][tc + 0] = v.x; tile[e][tc + 1] = v.y;
        tile[e][tc + 2] = v.z; tile[e][tc + 3] = v.w;
    }
    __syncthreads();

    #pragma unroll
    for (int j = 0; j < 4; ++j) {
        const int i = tr + j * 16;
        float4 v = make_float4(tile[tc + 0][i], tile[tc + 1][i], tile[tc + 2][i], tile[tc + 3][i]);
        const long o = (long)b * CHW_ + (long)(i0 + i) * C_ + e0 + tc;
        if (domask) {
            uint h[2], l[2];
            cvt_hl4(v, h, l);
            *reinterpret_cast<uint2*>(&mTh[o]) = make_uint2(h[0], h[1]);
            *reinterpret_cast<uint2*>(&mTl[o]) = make_uint2(l[0], l[1]);
        } else {
            uint h[2];
            cvt_h4(v, h);
            *reinterpret_cast<uint2*>(&fTh[o]) = make_uint2(h[0], h[1]);
        }
    }
}

// ===========================================================================
// NT MFMA GEMM (split-K, 3-pass hi/lo, in-loop cvt): part[z] = F.G^T chunk.
// Conflict-free staging map: srow = t&127 (phase-distinct banks), half = t>>7.
// Fused row sums -> fsum/gsum via per-thread atomics.
// ===========================================================================
__global__ __launch_bounds__(256, 3) void gemm_nt_mfma(
    const float* __restrict__ F, const float* __restrict__ G,
    float* __restrict__ part,
    float* __restrict__ fsum, float* __restrict__ gsum)
{
    __shared__ ushort Ah[128 * LDH], Al[128 * LDH], Bh[128 * LDH], Bl[128 * LDH];

    const int z  = blockIdx.z;
    const int b  = z >> 4;
    const int ks = z & (KS - 1);
    const int c0 = blockIdx.y * 128;
    const int d0 = blockIdx.x * 128;
    const float* Fb = F + (long)b * CHW_ + (long)ks * KCH;
    const float* Gb = G + (long)b * CHW_ + (long)ks * KCH;
    const bool doF = (blockIdx.x == 0);
    const bool doG = (blockIdx.y == 0);

    const int t    = threadIdx.x;
    const int srow = t & 127;           // staging row (conflict-free phases)
    const int skf  = (t >> 7) * 16;     // k-half within tile (0 / 16)
    const int lane = t & 63, w = t >> 6;
    const int col  = lane & 15, quad = lane >> 4;
    const int wm   = (w >> 1) * 64, wn = (w & 1) * 64;

    f32x4 acc[4][4] = {};
    float rsF = 0.0f, rsG = 0.0f;

    for (int kt = 0; kt < KCH; kt += BKT) {
        {
            const float* s = &Fb[(long)(c0 + srow) * HW_ + kt + skf];
            float4 v0 = *reinterpret_cast<const float4*>(s);
            float4 v1 = *reinterpret_cast<const float4*>(s + 4);
            float4 v2 = *reinterpret_cast<const float4*>(s + 8);
            float4 v3 = *reinterpret_cast<const float4*>(s + 12);
            if (doF) {
                rsF += (v0.x + v0.y + v0.z + v0.w) + (v1.x + v1.y + v1.z + v1.w)
                     + (v2.x + v2.y + v2.z + v2.w) + (v3.x + v3.y + v3.z + v3.w);
            }
            uint h[4], l[4];
            cvt_hl4(v0, h + 0, l + 0);
            cvt_hl4(v1, h + 2, l + 2);
            *reinterpret_cast<uint4*>(&Ah[srow * LDH + skf]) = make_uint4(h[0], h[1], h[2], h[3]);
            *reinterpret_cast<uint4*>(&Al[srow * LDH + skf]) = make_uint4(l[0], l[1], l[2], l[3]);
            cvt_hl4(v2, h + 0, l + 0);
            cvt_hl4(v3, h + 2, l + 2);
            *reinterpret_cast<uint4*>(&Ah[srow * LDH + skf + 8]) = make_uint4(h[0], h[1], h[2], h[3]);
            *reinterpret_cast<uint4*>(&Al[srow * LDH + skf + 8]) = make_uint4(l[0], l[1], l[2], l[3]);
        }
        {
            const float* s = &Gb[(long)(d0 + srow) * HW_ + kt + skf];
            float4 v0 = *reinterpret_cast<const float4*>(s);
            float4 v1 = *reinterpret_cast<const float4*>(s + 4);
            float4 v2 = *reinterpret_cast<const float4*>(s + 8);
            float4 v3 = *reinterpret_cast<const float4*>(s + 12);
            if (doG) {
                rsG += (v0.x + v0.y + v0.z + v0.w) + (v1.x + v1.y + v1.z + v1.w)
                     + (v2.x + v2.y + v2.z + v2.w) + (v3.x + v3.y + v3.z + v3.w);
            }
            uint h[4], l[4];
            cvt_hl4(v0, h + 0, l + 0);
            cvt_hl4(v1, h + 2, l + 2);
            *reinterpret_cast<uint4*>(&Bh[srow * LDH + skf]) = make_uint4(h[0], h[1], h[2], h[3]);
            *reinterpret_cast<uint4*>(&Bl[srow * LDH + skf]) = make_uint4(l[0], l[1], l[2], l[3]);
            cvt_hl4(v2, h + 0, l + 0);
            cvt_hl4(v3, h + 2, l + 2);
            *reinterpret_cast<uint4*>(&Bh[srow * LDH + skf + 8]) = make_uint4(h[0], h[1], h[2], h[3]);
            *reinterpret_cast<uint4*>(&Bl[srow * LDH + skf + 8]) = make_uint4(l[0], l[1], l[2], l[3]);
        }
        __syncthreads();

        bf16x8 bfh[4], bfl[4];
        #pragma unroll
        for (int tj = 0; tj < 4; ++tj) {
            const int r = (wn + tj * 16 + col) * LDH + quad * 8;
            bfh[tj] = *reinterpret_cast<const bf16x8*>(&Bh[r]);
            bfl[tj] = *reinterpret_cast<const bf16x8*>(&Bl[r]);
        }
        #pragma unroll
        for (int ti = 0; ti < 4; ++ti) {
            const int r = (wm + ti * 16 + col) * LDH + quad * 8;
            bf16x8 afh = *reinterpret_cast<const bf16x8*>(&Ah[r]);
            bf16x8 afl = *reinterpret_cast<const bf16x8*>(&Al[r]);
            #pragma unroll
            for (int tj = 0; tj < 4; ++tj) {
                acc[ti][tj] = MFMA_BF16(afh, bfh[tj], acc[ti][tj]);
                acc[ti][tj] = MFMA_BF16(afh, bfl[tj], acc[ti][tj]);
                acc[ti][tj] = MFMA_BF16(afl, bfh[tj], acc[ti][tj]);
            }
        }
        __syncthreads();
    }

    if (doF) atomicAdd(&fsum[b * C_ + c0 + srow], rsF);
    if (doG) atomicAdd(&gsum[b * C_ + d0 + srow], rsG);

    float* P = part + (long)z * C_ * C_;
    #pragma unroll
    for (int ti = 0; ti < 4; ++ti) {
        const int m = c0 + wm + ti * 16 + quad * 4;
        #pragma unroll
        for (int tj = 0; tj < 4; ++tj) {
            const int n = d0 + wn + tj * 16 + col;
            #pragma unroll
            for (int r = 0; r < 4; ++r)
                P[(long)(m + r) * C_ + n] = acc[ti][tj][r];
        }
    }
}

// ===========================================================================
// Stats pass, LDS-FREE direct-fragment: scores tile 128x64 via global uint4
// fragment loads (corr/mT are L2-hot, rows k-contiguous). No barriers in the
// K-loop. Emits per-tile softmax partials pmax/psum[row][i-tile (64-wide)].
// ===========================================================================
__global__ __launch_bounds__(256, 3) void gemm_stats_mfma(
    const ushort* __restrict__ corrh, const ushort* __restrict__ corrl,
    const ushort* __restrict__ mTh,   const ushort* __restrict__ mTl,
    float* __restrict__ pmax, float* __restrict__ psum)
{
    __shared__ float pm[2][128], ps[2][128];

    const int b  = blockIdx.z;
    const int m0 = blockIdx.y * 128;
    const int n0 = blockIdx.x * 64;
    const ushort* Ahb = corrh + (long)b * C_ * C_;
    const ushort* Alb = corrl + (long)b * C_ * C_;
    const ushort* Bhb = mTh + (long)b * CHW_;
    const ushort* Blb = mTl + (long)b * CHW_;

    const int t    = threadIdx.x;
    const int lane = t & 63, w = t >> 6;
    const int col  = lane & 15, quad = lane >> 4;
    const int wm   = (w >> 1) * 64, wn = (w & 1) * 32;

    f32x4 acc[4][2] = {};

    for (int kt = 0; kt < C_; kt += BKT) {
        bf16x8 bh[2], bl[2];
        #pragma unroll
        for (int tj = 0; tj < 2; ++tj) {
            const long ob = (long)(n0 + wn + tj * 16 + col) * C_ + kt + quad * 8;
            bh[tj] = *reinterpret_cast<const bf16x8*>(&Bhb[ob]);
            bl[tj] = *reinterpret_cast<const bf16x8*>(&Blb[ob]);
        }
        #pragma unroll
        for (int ti = 0; ti < 4; ++ti) {
            const long oa = (long)(m0 + wm + ti * 16 + col) * C_ + kt + quad * 8;
            bf16x8 ah = *reinterpret_cast<const bf16x8*>(&Ahb[oa]);
            bf16x8 al = *reinterpret_cast<const bf16x8*>(&Alb[oa]);
            #pragma unroll
            for (int tj = 0; tj < 2; ++tj) {
                acc[ti][tj] = MFMA_BF16(ah, bh[tj], acc[ti][tj]);
                acc[ti][tj] = MFMA_BF16(ah, bl[tj], acc[ti][tj]);
                acc[ti][tj] = MFMA_BF16(al, bh[tj], acc[ti][tj]);
            }
        }
    }

    // per-tile softmax partials (max & sum-exp over this block's 64 i's)
    #pragma unroll
    for (int ti = 0; ti < 4; ++ti) {
        #pragma unroll
        for (int r = 0; r < 4; ++r) {
            float mx = fmaxf(acc[ti][0][r], acc[ti][1][r]);
            mx = fmaxf(mx, __shfl_xor(mx, 1));
            mx = fmaxf(mx, __shfl_xor(mx, 2));
            mx = fmaxf(mx, __shfl_xor(mx, 4));
            mx = fmaxf(mx, __shfl_xor(mx, 8));
            float se = __expf(acc[ti][0][r] - mx) + __expf(acc[ti][1][r] - mx);
            se += __shfl_xor(se, 1);
            se += __shfl_xor(se, 2);
            se += __shfl_xor(se, 4);
            se += __shfl_xor(se, 8);
            if (col == 0) {
                const int rb = wm + ti * 16 + quad * 4 + r;
                pm[w & 1][rb] = mx;
                ps[w & 1][rb] = se;
            }
        }
    }
    __syncthreads();
    if (t < 128) {
        const float a0 = pm[0][t], a1 = pm[1][t];
        const float gm = fmaxf(a0, a1);
        const float gs = ps[0][t] * __expf(a0 - gm) + ps[1][t] * __expf(a1 - gm);
        const long rowg = (long)b * C_ + m0 + t;
        pmax[rowg * 64 + blockIdx.x] = gm;
        psum[rowg * 64 + blockIdx.x] = gs;
    }
}

// ===========================================================================
// Fused final, LDS-FREE direct-fragment: recompute scores tile (identical
// MFMA chain to stats), exp with precombined stats, v-GEMM, full epilogue.
// ===========================================================================
__global__ __launch_bounds__(256, 3) void gemm_fused_final(
    const ushort* __restrict__ corrh, const ushort* __restrict__ corrl,
    const ushort* __restrict__ mTh,   const ushort* __restrict__ mTl,
    const ushort* __restrict__ Wvh,   const ushort* __restrict__ fTh,
    const float* __restrict__ pmax,   const float* __restrict__ psum,
    const float* __restrict__ bv,     const float* __restrict__ fg,
    const float* __restrict__ mask,   const float* __restrict__ gamma,
    float* __restrict__ out)
{
    __shared__ float sm[128], si[128];

    const int b  = blockIdx.z;
    const int m0 = blockIdx.y * 128;        // c
    const int n0 = blockIdx.x * 64;         // i
    const ushort* Ahb = corrh + (long)b * C_ * C_;
    const ushort* Alb = corrl + (long)b * C_ * C_;
    const ushort* Bhb = mTh + (long)b * CHW_;
    const ushort* Blb = mTl + (long)b * CHW_;
    const ushort* Fb  = fTh + (long)b * CHW_;

    const int t    = threadIdx.x;
    const int lane = t & 63, w = t >> 6;
    const int col  = lane & 15, quad = lane >> 4;
    const int wm   = (w >> 1) * 64, wn = (w & 1) * 32;

    // combine per-row softmax stats into LDS (64 partials per row)
    if (t < 128) {
        const long rowg = (long)b * C_ + m0 + t;
        const float* pmr = pmax + rowg * 64;
        const float* psr = psum + rowg * 64;
        float gm = -INFINITY;
        for (int i = 0; i < 64; ++i) gm = fmaxf(gm, pmr[i]);
        float gs = 0.0f;
        for (int i = 0; i < 64; ++i) gs += psr[i] * __expf(pmr[i] - gm);
        sm[t] = gm;
        si[t] = 1.0f / gs;
    }
    __syncthreads();

    f32x4 acc_s[4][2] = {};
    f32x4 acc_v[4][2] = {};

    for (int kt = 0; kt < C_; kt += BKT) {
        bf16x8 bh[2], bl[2], bf[2];
        #pragma unroll
        for (int tj = 0; tj < 2; ++tj) {
            const long ob = (long)(n0 + wn + tj * 16 + col) * C_ + kt + quad * 8;
            bh[tj] = *reinterpret_cast<const bf16x8*>(&Bhb[ob]);
            bl[tj] = *reinterpret_cast<const bf16x8*>(&Blb[ob]);
            bf[tj] = *reinterpret_cast<const bf16x8*>(&Fb[ob]);
        }
        #pragma unroll
        for (int ti = 0; ti < 4; ++ti) {
            const long oa = (long)(m0 + wm + ti * 16 + col) * C_ + kt + quad * 8;
            bf16x8 ah = *reinterpret_cast<const bf16x8*>(&Ahb[oa]);
            bf16x8 al = *reinterpret_cast<const bf16x8*>(&Alb[oa]);
            bf16x8 aw = *reinterpret_cast<const bf16x8*>(&Wvh[oa]);
            #pragma unroll
            for (int tj = 0; tj < 2; ++tj) {
                acc_s[ti][tj] = MFMA_BF16(ah, bh[tj], acc_s[ti][tj]);
                acc_s[ti][tj] = MFMA_BF16(ah, bl[tj], acc_s[ti][tj]);
                acc_s[ti][tj] = MFMA_BF16(al, bh[tj], acc_s[ti][tj]);
                acc_v[ti][tj] = MFMA_BF16(aw, bf[tj], acc_v[ti][tj]);
            }
        }
    }

    // scores -> gamma-scaled probabilities
    const float g = gamma[0];
    #pragma unroll
    for (int ti = 0; ti < 4; ++ti) {
        #pragma unroll
        for (int r = 0; r < 4; ++r) {
            const int lrow = wm + ti * 16 + quad * 4 + r;
            const float mx  = sm[lrow];
            const float inv = si[lrow] * g;
            #pragma unroll
            for (int tj = 0; tj < 2; ++tj)
                acc_s[ti][tj][r] = __expf(acc_s[ti][tj][r] - mx) * inv;
        }
    }

    // epilogue
    #pragma unroll
    for (int ti = 0; ti < 4; ++ti) {
        const int m = m0 + wm + ti * 16 + quad * 4;
        #pragma unroll
        for (int r = 0; r < 4; ++r) {
            const float bvm = bv[m + r];
            #pragma unroll
            for (int tj = 0; tj < 2; ++tj) {
                const int n = n0 + wn + tj * 16 + col;
                const long e = (long)b * CHW_ + (long)(m + r) * HW_ + n;
                const float f  = fg[e];
                const float mk = mask[e];
                const float vv = acc_v[ti][tj][r] + bvm;
                out[e] = f * mk + (1.0f - mk) * acc_s[ti][tj][r] * vv;
            }
        }
    }
}

// ===========================================================================
// reduce split-K partials
// ===========================================================================
__global__ __launch_bounds__(256) void reduce_part(
    const float* __restrict__ part, float* __restrict__ S1)
{
    const long idx = (long)blockIdx.x * 256 + threadIdx.x;
    const int  b   = (int)(idx >> 16);
    const long e   = idx & 65535;
    const float* p = part + ((long)b * KS) * 65536 + e;
    float s = 0.0f;
    #pragma unroll
    for (int ks = 0; ks < KS; ++ks) s += p[(long)ks * 65536];
    S1[idx] = s;
}

__global__ __launch_bounds__(256) void uvw_kernel(
    const float* __restrict__ Wq, const float* __restrict__ Wk,
    const float* __restrict__ bk,
    const float* __restrict__ fsum, const float* __restrict__ gsum,
    float* __restrict__ u, float* __restrict__ wh)
{
    const int g = blockIdx.x * 256 + threadIdx.x;
    if (g < 2048) {
        const int b = g >> 8, c = g & 255;
        const float* w = Wq + (long)c * C_;
        const float* s = fsum + b * C_;
        float acc = 0.0f;
        for (int e = 0; e < C_; ++e) acc = fmaf(w[e], s[e], acc);
        u[g] = acc;
    } else {
        const int g2 = g - 2048;
        const int b = g2 >> 8, d = g2 & 255;
        const float* w = Wk + (long)d * C_;
        const float* s = gsum + b * C_;
        float acc = 0.0f;
        for (int f = 0; f < C_; ++f) acc = fmaf(w[f], s[f], acc);
        wh[g2] = acc + (float)HW_ * bk[d];
    }
}

#define BK64 16
#define LDT64 68
__global__ __launch_bounds__(256) void gemm_nt64(
    const float* __restrict__ S1, const float* __restrict__ Wk,
    float* __restrict__ T)
{
    __shared__ float As[BK64][LDT64];
    __shared__ float Bs[BK64][LDT64];
    const int r0 = blockIdx.y * 64;
    const int d0 = blockIdx.x * 64;
    const int t   = threadIdx.x;
    const int tx  = t & 15, ty = t >> 4;
    const int tx4 = tx * 4, ty4 = ty * 4;
    const int am  = t >> 2, ak4 = (t & 3) * 4;

    float acc[4][4] = {};
    for (int k0 = 0; k0 < C_; k0 += BK64) {
        float4 av = *reinterpret_cast<const float4*>(&S1[(long)(r0 + am) * C_ + k0 + ak4]);
        float4 bw = *reinterpret_cast<const float4*>(&Wk[(long)(d0 + am) * C_ + k0 + ak4]);
        As[ak4+0][am]=av.x; As[ak4+1][am]=av.y; As[ak4+2][am]=av.z; As[ak4+3][am]=av.w;
        Bs[ak4+0][am]=bw.x; Bs[ak4+1][am]=bw.y; Bs[ak4+2][am]=bw.z; Bs[ak4+3][am]=bw.w;
        __syncthreads();
        #pragma unroll
        for (int kk = 0; kk < BK64; ++kk) {
            float4 a = *reinterpret_cast<const float4*>(&As[kk][ty4]);
            float4 x = *reinterpret_cast<const float4*>(&Bs[kk][tx4]);
            const float ar[4] = {a.x,a.y,a.z,a.w};
            const float xr[4] = {x.x,x.y,x.z,x.w};
            #pragma unroll
            for (int r = 0; r < 4; ++r)
                #pragma unroll
                for (int s = 0; s < 4; ++s)
                    acc[r][s] = fmaf(ar[r], xr[s], acc[r][s]);
        }
        __syncthreads();
    }
    #pragma unroll
    for (int r = 0; r < 4; ++r) {
        float4 o; o.x=acc[r][0]; o.y=acc[r][1]; o.z=acc[r][2]; o.w=acc[r][3];
        *reinterpret_cast<float4*>(&T[(long)(r0 + ty4 + r) * C_ + d0 + tx4]) = o;
    }
}

// corr = Wq*T + u*bk^T + bq*wh^T, emitted directly as bf16 hi/lo
__global__ __launch_bounds__(256) void gemm_nn64_rank1(
    const float* __restrict__ Wq, const float* __restrict__ T,
    const float* __restrict__ u,  const float* __restrict__ bk,
    const float* __restrict__ bq, const float* __restrict__ wh,
    ushort* __restrict__ corrh, ushort* __restrict__ corrl)
{
    __shared__ float As[BK64][LDT64];
    __shared__ float Bs[BK64][LDT64];
    const int b  = blockIdx.z;
    const int m0 = blockIdx.y * 64;
    const int n0 = blockIdx.x * 64;
    const float* Tb = T + (long)b * C_ * C_;

    const int t   = threadIdx.x;
    const int tx  = t & 15, ty = t >> 4;
    const int tx4 = tx * 4, ty4 = ty * 4;
    const int am  = t >> 2, ak4 = (t & 3) * 4;
    const int xk  = ty,     xn4 = tx4;

    float acc[4][4] = {};
    for (int k0 = 0; k0 < C_; k0 += BK64) {
        float4 av = *reinterpret_cast<const float4*>(&Wq[(long)(m0 + am) * C_ + k0 + ak4]);
        float4 xv = *reinterpret_cast<const float4*>(&Tb[(long)(k0 + xk) * C_ + n0 + xn4]);
        As[ak4+0][am]=av.x; As[ak4+1][am]=av.y; As[ak4+2][am]=av.z; As[ak4+3][am]=av.w;
        *reinterpret_cast<float4*>(&Bs[xk][xn4]) = xv;
        __syncthreads();
        #pragma unroll
        for (int kk = 0; kk < BK64; ++kk) {
            float4 a = *reinterpret_cast<const float4*>(&As[kk][ty4]);
            float4 x = *reinterpret_cast<const float4*>(&Bs[kk][tx4]);
            const float ar[4] = {a.x,a.y,a.z,a.w};
            const float xr[4] = {x.x,x.y,x.z,x.w};
            #pragma unroll
            for (int r = 0; r < 4; ++r)
                #pragma unroll
                for (int s = 0; s < 4; ++s)
                    acc[r][s] = fmaf(ar[r], xr[s], acc[r][s]);
        }
        __syncthreads();
    }

    float4 bkv = *reinterpret_cast<const float4*>(&bk[n0 + tx4]);
    float4 whv = *reinterpret_cast<const float4*>(&wh[b * C_ + n0 + tx4]);
    #pragma unroll
    for (int r = 0; r < 4; ++r) {
        const int m = m0 + ty4 + r;
        const float um = u[b * C_ + m];
        const float bm = bq[m];
        float4 o;
        o.x = acc[r][0] + um*bkv.x + bm*whv.x;
        o.y = acc[r][1] + um*bkv.y + bm*whv.y;
        o.z = acc[r][2] + um*bkv.z + bm*whv.z;
        o.w = acc[r][3] + um*bkv.w + bm*whv.w;
        uint h[2], l[2];
        cvt_hl4(o, h, l);
        const long e = (long)b * C_ * C_ + (long)m * C_ + n0 + tx4;
        *reinterpret_cast<uint2*>(&corrh[e]) = make_uint2(h[0], h[1]);
        *reinterpret_cast<uint2*>(&corrl[e]) = make_uint2(l[0], l[1]);
    }
}

// ===========================================================================
extern "C" void kernel_launch(void* const* d_in, const int* in_sizes, int n_in,
                              void* d_out, int out_size, void* d_ws, size_t ws_size,
                              hipStream_t stream)
{
    const float* fg    = (const float*)d_in[0];
    const float* bg    = (const float*)d_in[1];
    const float* mask  = (const float*)d_in[2];
    const float* Wq    = (const float*)d_in[3];
    const float* bq    = (const float*)d_in[4];
    const float* Wk    = (const float*)d_in[5];
    const float* bk    = (const float*)d_in[6];
    const float* Wv    = (const float*)d_in[7];
    const float* bv    = (const float*)d_in[8];
    const float* gamma = (const float*)d_in[9];
    float* out = (float*)d_out;

    // ---- workspace layout (bytes) ----
    char* ws = (char*)d_ws;
    float*  part   = (float*)(ws);                        // 33,554,432
    ushort* mTh    = (ushort*)(ws + 33554432);            // 16,777,216
    ushort* mTl    = (ushort*)(ws + 50331648);            // 16,777,216
    ushort* fTh    = (ushort*)(ws + 67108864);            // 16,777,216
    float*  S1     = (float*)(ws + 83886080);             // 2,097,152
    float*  T      = (float*)(ws + 85983232);             // 2,097,152
    ushort* corrh  = (ushort*)(ws + 88080384);            // 1,048,576
    ushort* corrl  = (ushort*)(ws + 89128960);            // 1,048,576
    ushort* Wvh    = (ushort*)(ws + 90177536);            // 131,072
    float*  fsum   = (float*)(ws + 90308608);             // 8,192
    float*  gsum   = (float*)(ws + 90316800);             // 8,192
    float*  u      = (float*)(ws + 90324992);             // 8,192
    float*  wh     = (float*)(ws + 90333184);             // 8,192
    float*  pmax   = (float*)(ws + 90341376);             // 524,288
    float*  psum   = (float*)(ws + 90865664);             // 524,288

    const dim3 blk(256);

    // 0. zero the atomic accumulators (fsum+gsum contiguous 16 kB)
    hipMemsetAsync(fsum, 0, 16384, stream);

    // 1. transposed conversions: mask -> maskT h/l, fg -> fgT h; Wv -> hi
    conv_transpose<<<dim3(HW_ / 64, C_ / 64, 2 * B_), blk, 0, stream>>>(
        mask, fg, mTh, mTl, fTh);
    conv_w<<<dim3(64), blk, 0, stream>>>(Wv, Wvh);

    // 2. S1 = F*G^T via split-K MFMA (fused row sums), reduce
    gemm_nt_mfma<<<dim3(2, 2, B_ * KS), blk, 0, stream>>>(fg, bg, part, fsum, gsum);
    reduce_part<<<dim3(B_ * C_ * C_ / 256), blk, 0, stream>>>(part, S1);

    // 3. rank-1 helper vectors
    uvw_kernel<<<dim3(16), blk, 0, stream>>>(Wq, Wk, bk, fsum, gsum, u, wh);

    // 4. T = S1 * Wk^T ; corr (bf16 h/l) = Wq*T + u*bk^T + bq*wh^T
    gemm_nt64<<<dim3(C_ / 64, B_ * C_ / 64), blk, 0, stream>>>(S1, Wk, T);
    gemm_nn64_rank1<<<dim3(4, 4, B_), blk, 0, stream>>>(Wq, T, u, bk, bq, wh, corrh, corrl);

    // 5. stats pass (LDS-free, no S materialization)
    gemm_stats_mfma<<<dim3(HW_ / 64, C_ / 128, B_), blk, 0, stream>>>(
        corrh, corrl, mTh, mTl, pmax, psum);

    // 6. fused recompute + v-GEMM + finalize (LDS-free)
    gemm_fused_final<<<dim3(HW_ / 64, C_ / 128, B_), blk, 0, stream>>>(
        corrh, corrl, mTh, mTl, Wvh, fTh, pmax, psum, bv, fg, mask, gamma, out);
}

// Round 8
// 276.158 us; speedup vs baseline: 1.4700x; 1.4700x over previous
//
#include <hip/hip_runtime.h>
#include <math.h>

#define B_    8
#define C_    256
#define HW_   4096
#define CHW_  ((long)C_ * HW_)

#define BKT   32      // bf16 K per tile
#define LDH   40      // LDS row stride in ushorts (gemm_nt staging)
#define LDI   132     // fp32 tile row stride (128 + 4 pad), 528 B = 16B-aligned
#define KS    16      // split-K for F*G^T
#define KCH   (HW_ / KS)   // 256

typedef __attribute__((ext_vector_type(8))) short bf16x8;
typedef __attribute__((ext_vector_type(4))) float f32x4;
#define MFMA_BF16(a, b, c) __builtin_amdgcn_mfma_f32_16x16x32_bf16((a), (b), (c), 0, 0, 0)

union frag_u { uint4 u4; bf16x8 bf; };

// fp32x4 -> bf16 hi + lo residual, packed 2/dword
__device__ __forceinline__ void cvt_hl4(const float4 f, uint* h, uint* l) {
    uint u0 = __float_as_uint(f.x), u1 = __float_as_uint(f.y),
         u2 = __float_as_uint(f.z), u3 = __float_as_uint(f.w);
    uint h0 = (u0 + 0x8000u) & 0xFFFF0000u, h1 = (u1 + 0x8000u) & 0xFFFF0000u,
         h2 = (u2 + 0x8000u) & 0xFFFF0000u, h3 = (u3 + 0x8000u) & 0xFFFF0000u;
    h[0] = (h0 >> 16) | h1;
    h[1] = (h2 >> 16) | h3;
    float l0 = f.x - __uint_as_float(h0), l1 = f.y - __uint_as_float(h1),
          l2 = f.z - __uint_as_float(h2), l3 = f.w - __uint_as_float(h3);
    uint a0 = __float_as_uint(l0) & 0xFFFF0000u, a1 = __float_as_uint(l1) & 0xFFFF0000u,
         a2 = __float_as_uint(l2) & 0xFFFF0000u, a3 = __float_as_uint(l3) & 0xFFFF0000u;
    l[0] = (a0 >> 16) | a1;
    l[1] = (a2 >> 16) | a3;
}
__device__ __forceinline__ void cvt_h4(const float4 f, uint* h) {
    uint u0 = __float_as_uint(f.x), u1 = __float_as_uint(f.y),
         u2 = __float_as_uint(f.z), u3 = __float_as_uint(f.w);
    uint h0 = (u0 + 0x8000u) & 0xFFFF0000u, h1 = (u1 + 0x8000u) & 0xFFFF0000u,
         h2 = (u2 + 0x8000u) & 0xFFFF0000u, h3 = (u3 + 0x8000u) & 0xFFFF0000u;
    h[0] = (h0 >> 16) | h1;
    h[1] = (h2 >> 16) | h3;
}

// 8 fp32 (k-contiguous) -> bf16x8 hi + bf16x8 lo fragments
__device__ __forceinline__ void cvt8_hl(const float* f, bf16x8* bh, bf16x8* bl) {
    frag_u H, L;
    uint hw[8];
    #pragma unroll
    for (int j = 0; j < 4; ++j) {
        uint u0 = __float_as_uint(f[2*j]), u1 = __float_as_uint(f[2*j+1]);
        uint h0 = (u0 + 0x8000u) & 0xFFFF0000u;
        uint h1 = (u1 + 0x8000u) & 0xFFFF0000u;
        ((uint*)&H.u4)[j] = (h0 >> 16) | h1;
        hw[2*j] = h0; hw[2*j+1] = h1;
    }
    #pragma unroll
    for (int j = 0; j < 4; ++j) {
        float l0 = f[2*j]   - __uint_as_float(hw[2*j]);
        float l1 = f[2*j+1] - __uint_as_float(hw[2*j+1]);
        ((uint*)&L.u4)[j] = ((__float_as_uint(l0) & 0xFFFF0000u) >> 16)
                          |  (__float_as_uint(l1) & 0xFFFF0000u);
    }
    *bh = H.bf; *bl = L.bf;
}
__device__ __forceinline__ void cvt8_h(const float* f, bf16x8* bh) {
    frag_u H;
    #pragma unroll
    for (int j = 0; j < 4; ++j) {
        uint h0 = (__float_as_uint(f[2*j])   + 0x8000u) & 0xFFFF0000u;
        uint h1 = (__float_as_uint(f[2*j+1]) + 0x8000u) & 0xFFFF0000u;
        ((uint*)&H.u4)[j] = (h0 >> 16) | h1;
    }
    *bh = H.bf;
}

// Wv -> bf16 hi copy
__global__ __launch_bounds__(256) void conv_w(
    const float* __restrict__ Wv, ushort* __restrict__ Wvh)
{
    const int i = (blockIdx.x * 256 + threadIdx.x) * 4;
    float4 v = *reinterpret_cast<const float4*>(&Wv[i]);
    uint h[2];
    cvt_h4(v, h);
    *reinterpret_cast<uint2*>(&Wvh[i]) = make_uint2(h[0], h[1]);
}

// ===========================================================================
// NT MFMA GEMM (split-K, 3-pass hi/lo, in-loop cvt): part[z] = F.G^T chunk.
// Fused row sums -> fsum/gsum via atomics.
// ===========================================================================
__global__ __launch_bounds__(256, 3) void gemm_nt_mfma(
    const float* __restrict__ F, const float* __restrict__ G,
    float* __restrict__ part,
    float* __restrict__ fsum, float* __restrict__ gsum)
{
    __shared__ ushort Ah[128 * LDH], Al[128 * LDH], Bh[128 * LDH], Bl[128 * LDH];

    const int z  = blockIdx.z;
    const int b  = z >> 4;
    const int ks = z & (KS - 1);
    const int c0 = blockIdx.y * 128;
    const int d0 = blockIdx.x * 128;
    const float* Fb = F + (long)b * CHW_ + (long)ks * KCH;
    const float* Gb = G + (long)b * CHW_ + (long)ks * KCH;
    const bool doF = (blockIdx.x == 0);
    const bool doG = (blockIdx.y == 0);

    const int t    = threadIdx.x;
    const int srow = t & 127;
    const int skf  = (t >> 7) * 16;
    const int lane = t & 63, w = t >> 6;
    const int col  = lane & 15, quad = lane >> 4;
    const int wm   = (w >> 1) * 64, wn = (w & 1) * 64;

    f32x4 acc[4][4] = {};
    float rsF = 0.0f, rsG = 0.0f;

    for (int kt = 0; kt < KCH; kt += BKT) {
        {
            const float* s = &Fb[(long)(c0 + srow) * HW_ + kt + skf];
            float4 v0 = *reinterpret_cast<const float4*>(s);
            float4 v1 = *reinterpret_cast<const float4*>(s + 4);
            float4 v2 = *reinterpret_cast<const float4*>(s + 8);
            float4 v3 = *reinterpret_cast<const float4*>(s + 12);
            if (doF) {
                rsF += (v0.x + v0.y + v0.z + v0.w) + (v1.x + v1.y + v1.z + v1.w)
                     + (v2.x + v2.y + v2.z + v2.w) + (v3.x + v3.y + v3.z + v3.w);
            }
            uint h[4], l[4];
            cvt_hl4(v0, h + 0, l + 0);
            cvt_hl4(v1, h + 2, l + 2);
            *reinterpret_cast<uint4*>(&Ah[srow * LDH + skf]) = make_uint4(h[0], h[1], h[2], h[3]);
            *reinterpret_cast<uint4*>(&Al[srow * LDH + skf]) = make_uint4(l[0], l[1], l[2], l[3]);
            cvt_hl4(v2, h + 0, l + 0);
            cvt_hl4(v3, h + 2, l + 2);
            *reinterpret_cast<uint4*>(&Ah[srow * LDH + skf + 8]) = make_uint4(h[0], h[1], h[2], h[3]);
            *reinterpret_cast<uint4*>(&Al[srow * LDH + skf + 8]) = make_uint4(l[0], l[1], l[2], l[3]);
        }
        {
            const float* s = &Gb[(long)(d0 + srow) * HW_ + kt + skf];
            float4 v0 = *reinterpret_cast<const float4*>(s);
            float4 v1 = *reinterpret_cast<const float4*>(s + 4);
            float4 v2 = *reinterpret_cast<const float4*>(s + 8);
            float4 v3 = *reinterpret_cast<const float4*>(s + 12);
            if (doG) {
                rsG += (v0.x + v0.y + v0.z + v0.w) + (v1.x + v1.y + v1.z + v1.w)
                     + (v2.x + v2.y + v2.z + v2.w) + (v3.x + v3.y + v3.z + v3.w);
            }
            uint h[4], l[4];
            cvt_hl4(v0, h + 0, l + 0);
            cvt_hl4(v1, h + 2, l + 2);
            *reinterpret_cast<uint4*>(&Bh[srow * LDH + skf]) = make_uint4(h[0], h[1], h[2], h[3]);
            *reinterpret_cast<uint4*>(&Bl[srow * LDH + skf]) = make_uint4(l[0], l[1], l[2], l[3]);
            cvt_hl4(v2, h + 0, l + 0);
            cvt_hl4(v3, h + 2, l + 2);
            *reinterpret_cast<uint4*>(&Bh[srow * LDH + skf + 8]) = make_uint4(h[0], h[1], h[2], h[3]);
            *reinterpret_cast<uint4*>(&Bl[srow * LDH + skf + 8]) = make_uint4(l[0], l[1], l[2], l[3]);
        }
        __syncthreads();

        bf16x8 bfh[4], bfl[4];
        #pragma unroll
        for (int tj = 0; tj < 4; ++tj) {
            const int r = (wn + tj * 16 + col) * LDH + quad * 8;
            bfh[tj] = *reinterpret_cast<const bf16x8*>(&Bh[r]);
            bfl[tj] = *reinterpret_cast<const bf16x8*>(&Bl[r]);
        }
        #pragma unroll
        for (int ti = 0; ti < 4; ++ti) {
            const int r = (wm + ti * 16 + col) * LDH + quad * 8;
            bf16x8 afh = *reinterpret_cast<const bf16x8*>(&Ah[r]);
            bf16x8 afl = *reinterpret_cast<const bf16x8*>(&Al[r]);
            #pragma unroll
            for (int tj = 0; tj < 4; ++tj) {
                acc[ti][tj] = MFMA_BF16(afh, bfh[tj], acc[ti][tj]);
                acc[ti][tj] = MFMA_BF16(afh, bfl[tj], acc[ti][tj]);
                acc[ti][tj] = MFMA_BF16(afl, bfh[tj], acc[ti][tj]);
            }
        }
        __syncthreads();
    }

    if (doF) atomicAdd(&fsum[b * C_ + c0 + srow], rsF);
    if (doG) atomicAdd(&gsum[b * C_ + d0 + srow], rsG);

    float* P = part + (long)z * C_ * C_;
    #pragma unroll
    for (int ti = 0; ti < 4; ++ti) {
        const int m = c0 + wm + ti * 16 + quad * 4;
        #pragma unroll
        for (int tj = 0; tj < 4; ++tj) {
            const int n = d0 + wn + tj * 16 + col;
            #pragma unroll
            for (int r = 0; r < 4; ++r)
                P[(long)(m + r) * C_ + n] = acc[ti][tj][r];
        }
    }
}

// ===========================================================================
// Stats pass: 128x128 tile. A = corr h/l DIRECT from global (L2-resident);
// B = mask fp32 staged natural-layout in LDS, transposed+converted to bf16
// h/l fragments in registers. Emits per-tile softmax partials.
// ===========================================================================
__global__ __launch_bounds__(256, 3) void gemm_stats_mfma(
    const ushort* __restrict__ corrh, const ushort* __restrict__ corrl,
    const float* __restrict__ mask,
    float* __restrict__ pmax, float* __restrict__ psum)
{
    __shared__ float Ms[32 * LDI];
    __shared__ float pm[2][128], ps[2][128];

    const int b  = blockIdx.z;
    const int m0 = blockIdx.y * 128;
    const int n0 = blockIdx.x * 128;
    const ushort* Ahb = corrh + (long)b * C_ * C_;
    const ushort* Alb = corrl + (long)b * C_ * C_;
    const float*  Mb  = mask + (long)b * CHW_;

    const int t    = threadIdx.x;
    const int se   = t >> 3;            // staging e-row 0..31
    const int si4  = (t & 7) * 4;       // staging i-offset
    const int lane = t & 63, w = t >> 6;
    const int col  = lane & 15, quad = lane >> 4;
    const int wm   = (w >> 1) * 64, wn = (w & 1) * 64;

    f32x4 acc[4][4] = {};

    for (int kt = 0; kt < C_; kt += BKT) {
        __syncthreads();
        #pragma unroll
        for (int rep = 0; rep < 4; ++rep) {
            const int i = rep * 32 + si4;
            float4 v = *reinterpret_cast<const float4*>(&Mb[(long)(kt + se) * HW_ + n0 + i]);
            *reinterpret_cast<float4*>(&Ms[se * LDI + i]) = v;
        }
        __syncthreads();

        // A fragments direct from global (L2-hot)
        bf16x8 ah[4], al[4];
        #pragma unroll
        for (int ti = 0; ti < 4; ++ti) {
            const long oa = (long)(m0 + wm + ti * 16 + col) * C_ + kt + quad * 8;
            ah[ti] = *reinterpret_cast<const bf16x8*>(&Ahb[oa]);
            al[ti] = *reinterpret_cast<const bf16x8*>(&Alb[oa]);
        }
        // B fragments: transposed column reads + cvt
        #pragma unroll
        for (int tj = 0; tj < 4; ++tj) {
            const int i = wn + tj * 16 + col;
            float fv[8];
            #pragma unroll
            for (int j = 0; j < 8; ++j)
                fv[j] = Ms[(quad * 8 + j) * LDI + i];
            bf16x8 bh, bl;
            cvt8_hl(fv, &bh, &bl);
            #pragma unroll
            for (int ti = 0; ti < 4; ++ti) {
                acc[ti][tj] = MFMA_BF16(ah[ti], bh, acc[ti][tj]);
                acc[ti][tj] = MFMA_BF16(ah[ti], bl, acc[ti][tj]);
                acc[ti][tj] = MFMA_BF16(al[ti], bh, acc[ti][tj]);
            }
        }
    }

    // per-tile softmax partials (max & sum-exp over this block's 128 i's)
    #pragma unroll
    for (int ti = 0; ti < 4; ++ti) {
        #pragma unroll
        for (int r = 0; r < 4; ++r) {
            float mx = fmaxf(fmaxf(acc[ti][0][r], acc[ti][1][r]),
                             fmaxf(acc[ti][2][r], acc[ti][3][r]));
            mx = fmaxf(mx, __shfl_xor(mx, 1));
            mx = fmaxf(mx, __shfl_xor(mx, 2));
            mx = fmaxf(mx, __shfl_xor(mx, 4));
            mx = fmaxf(mx, __shfl_xor(mx, 8));
            float se2 = __expf(acc[ti][0][r] - mx) + __expf(acc[ti][1][r] - mx)
                      + __expf(acc[ti][2][r] - mx) + __expf(acc[ti][3][r] - mx);
            se2 += __shfl_xor(se2, 1);
            se2 += __shfl_xor(se2, 2);
            se2 += __shfl_xor(se2, 4);
            se2 += __shfl_xor(se2, 8);
            if (col == 0) {
                const int rb = wm + ti * 16 + quad * 4 + r;
                pm[w & 1][rb] = mx;
                ps[w & 1][rb] = se2;
            }
        }
    }
    __syncthreads();
    if (t < 128) {
        const float a0 = pm[0][t], a1 = pm[1][t];
        const float gm = fmaxf(a0, a1);
        const float gs = ps[0][t] * __expf(a0 - gm) + ps[1][t] * __expf(a1 - gm);
        const long rowg = (long)b * C_ + m0 + t;
        pmax[rowg * 32 + blockIdx.x] = gm;
        psum[rowg * 32 + blockIdx.x] = gs;
    }
}

// ===========================================================================
// Fused final: 128x128 tile. Recompute scores (identical chain) + v-GEMM in
// one K-loop. A-side (corr h/l, Wvh) direct global; B-side (mask, fg) staged
// fp32 in LDS, transposed+converted in registers. Full epilogue.
// ===========================================================================
__global__ __launch_bounds__(256, 2) void gemm_fused_final(
    const ushort* __restrict__ corrh, const ushort* __restrict__ corrl,
    const ushort* __restrict__ Wvh,
    const float* __restrict__ mask,   const float* __restrict__ fg,
    const float* __restrict__ pmax,   const float* __restrict__ psum,
    const float* __restrict__ bv,     const float* __restrict__ gamma,
    float* __restrict__ out)
{
    __shared__ float Ms[32 * LDI];
    __shared__ float Fs[32 * LDI];
    __shared__ float sm[128], si[128];

    const int b  = blockIdx.z;
    const int m0 = blockIdx.y * 128;        // c
    const int n0 = blockIdx.x * 128;        // i
    const ushort* Ahb = corrh + (long)b * C_ * C_;
    const ushort* Alb = corrl + (long)b * C_ * C_;
    const float*  Mb  = mask + (long)b * CHW_;
    const float*  Fgb = fg   + (long)b * CHW_;

    const int t    = threadIdx.x;
    const int se   = t >> 3;
    const int si4  = (t & 7) * 4;
    const int lane = t & 63, w = t >> 6;
    const int col  = lane & 15, quad = lane >> 4;
    const int wm   = (w >> 1) * 64, wn = (w & 1) * 64;

    // combine per-row softmax stats into LDS (32 partials per row)
    if (t < 128) {
        const long rowg = (long)b * C_ + m0 + t;
        const float* pmr = pmax + rowg * 32;
        const float* psr = psum + rowg * 32;
        float gm = -INFINITY;
        #pragma unroll
        for (int i = 0; i < 32; ++i) gm = fmaxf(gm, pmr[i]);
        float gs = 0.0f;
        #pragma unroll
        for (int i = 0; i < 32; ++i) gs += psr[i] * __expf(pmr[i] - gm);
        sm[t] = gm;
        si[t] = 1.0f / gs;
    }

    f32x4 acc_s[4][4] = {};
    f32x4 acc_v[4][4] = {};

    for (int kt = 0; kt < C_; kt += BKT) {
        __syncthreads();
        #pragma unroll
        for (int rep = 0; rep < 4; ++rep) {
            const int i = rep * 32 + si4;
            float4 vm = *reinterpret_cast<const float4*>(&Mb[(long)(kt + se) * HW_ + n0 + i]);
            float4 vf = *reinterpret_cast<const float4*>(&Fgb[(long)(kt + se) * HW_ + n0 + i]);
            *reinterpret_cast<float4*>(&Ms[se * LDI + i]) = vm;
            *reinterpret_cast<float4*>(&Fs[se * LDI + i]) = vf;
        }
        __syncthreads();

        bf16x8 ah[4], al[4], aw[4];
        #pragma unroll
        for (int ti = 0; ti < 4; ++ti) {
            const long oa = (long)(m0 + wm + ti * 16 + col) * C_ + kt + quad * 8;
            ah[ti] = *reinterpret_cast<const bf16x8*>(&Ahb[oa]);
            al[ti] = *reinterpret_cast<const bf16x8*>(&Alb[oa]);
            aw[ti] = *reinterpret_cast<const bf16x8*>(&Wvh[oa]);
        }
        #pragma unroll
        for (int tj = 0; tj < 4; ++tj) {
            const int i = wn + tj * 16 + col;
            float fv[8], gv[8];
            #pragma unroll
            for (int j = 0; j < 8; ++j) {
                fv[j] = Ms[(quad * 8 + j) * LDI + i];
                gv[j] = Fs[(quad * 8 + j) * LDI + i];
            }
            bf16x8 bh, bl, bf;
            cvt8_hl(fv, &bh, &bl);
            cvt8_h(gv, &bf);
            #pragma unroll
            for (int ti = 0; ti < 4; ++ti) {
                acc_s[ti][tj] = MFMA_BF16(ah[ti], bh, acc_s[ti][tj]);
                acc_s[ti][tj] = MFMA_BF16(ah[ti], bl, acc_s[ti][tj]);
                acc_s[ti][tj] = MFMA_BF16(al[ti], bh, acc_s[ti][tj]);
                acc_v[ti][tj] = MFMA_BF16(aw[ti], bf, acc_v[ti][tj]);
            }
        }
    }

    // scores -> gamma-scaled probabilities
    const float g = gamma[0];
    #pragma unroll
    for (int ti = 0; ti < 4; ++ti) {
        #pragma unroll
        for (int r = 0; r < 4; ++r) {
            const int lrow = wm + ti * 16 + quad * 4 + r;
            const float mx  = sm[lrow];
            const float inv = si[lrow] * g;
            #pragma unroll
            for (int tj = 0; tj < 4; ++tj)
                acc_s[ti][tj][r] = __expf(acc_s[ti][tj][r] - mx) * inv;
        }
    }

    // epilogue
    #pragma unroll
    for (int ti = 0; ti < 4; ++ti) {
        const int m = m0 + wm + ti * 16 + quad * 4;
        #pragma unroll
        for (int r = 0; r < 4; ++r) {
            const float bvm = bv[m + r];
            #pragma unroll
            for (int tj = 0; tj < 4; ++tj) {
                const int n = n0 + wn + tj * 16 + col;
                const long e = (long)b * CHW_ + (long)(m + r) * HW_ + n;
                const float f  = fg[e];
                const float mk = mask[e];
                const float vv = acc_v[ti][tj][r] + bvm;
                out[e] = f * mk + (1.0f - mk) * acc_s[ti][tj][r] * vv;
            }
        }
    }
}

// ===========================================================================
// reduce split-K partials
// ===========================================================================
__global__ __launch_bounds__(256) void reduce_part(
    const float* __restrict__ part, float* __restrict__ S1)
{
    const long idx = (long)blockIdx.x * 256 + threadIdx.x;
    const int  b   = (int)(idx >> 16);
    const long e   = idx & 65535;
    const float* p = part + ((long)b * KS) * 65536 + e;
    float s = 0.0f;
    #pragma unroll
    for (int ks = 0; ks < KS; ++ks) s += p[(long)ks * 65536];
    S1[idx] = s;
}

#define BK64 16
#define LDT64 68
__global__ __launch_bounds__(256) void gemm_nt64(
    const float* __restrict__ S1, const float* __restrict__ Wk,
    float* __restrict__ T)
{
    __shared__ float As[BK64][LDT64];
    __shared__ float Bs[BK64][LDT64];
    const int r0 = blockIdx.y * 64;
    const int d0 = blockIdx.x * 64;
    const int t   = threadIdx.x;
    const int tx  = t & 15, ty = t >> 4;
    const int tx4 = tx * 4, ty4 = ty * 4;
    const int am  = t >> 2, ak4 = (t & 3) * 4;

    float acc[4][4] = {};
    for (int k0 = 0; k0 < C_; k0 += BK64) {
        float4 av = *reinterpret_cast<const float4*>(&S1[(long)(r0 + am) * C_ + k0 + ak4]);
        float4 bw = *reinterpret_cast<const float4*>(&Wk[(long)(d0 + am) * C_ + k0 + ak4]);
        As[ak4+0][am]=av.x; As[ak4+1][am]=av.y; As[ak4+2][am]=av.z; As[ak4+3][am]=av.w;
        Bs[ak4+0][am]=bw.x; Bs[ak4+1][am]=bw.y; Bs[ak4+2][am]=bw.z; Bs[ak4+3][am]=bw.w;
        __syncthreads();
        #pragma unroll
        for (int kk = 0; kk < BK64; ++kk) {
            float4 a = *reinterpret_cast<const float4*>(&As[kk][ty4]);
            float4 x = *reinterpret_cast<const float4*>(&Bs[kk][tx4]);
            const float ar[4] = {a.x,a.y,a.z,a.w};
            const float xr[4] = {x.x,x.y,x.z,x.w};
            #pragma unroll
            for (int r = 0; r < 4; ++r)
                #pragma unroll
                for (int s = 0; s < 4; ++s)
                    acc[r][s] = fmaf(ar[r], xr[s], acc[r][s]);
        }
        __syncthreads();
    }
    #pragma unroll
    for (int r = 0; r < 4; ++r) {
        float4 o; o.x=acc[r][0]; o.y=acc[r][1]; o.z=acc[r][2]; o.w=acc[r][3];
        *reinterpret_cast<float4*>(&T[(long)(r0 + ty4 + r) * C_ + d0 + tx4]) = o;
    }
}

// corr = Wq*T + u*bk^T + bq*wh^T -> bf16 h/l.  u, wh computed inline.
__global__ __launch_bounds__(256) void gemm_nn64_rank1(
    const float* __restrict__ Wq, const float* __restrict__ T,
    const float* __restrict__ Wk, const float* __restrict__ bk,
    const float* __restrict__ bq,
    const float* __restrict__ fsum, const float* __restrict__ gsum,
    ushort* __restrict__ corrh, ushort* __restrict__ corrl)
{
    __shared__ float As[BK64][LDT64];
    __shared__ float Bs[BK64][LDT64];
    __shared__ float u_s[64], wh_s[64];
    const int b  = blockIdx.z;
    const int m0 = blockIdx.y * 64;
    const int n0 = blockIdx.x * 64;
    const float* Tb = T + (long)b * C_ * C_;

    const int t   = threadIdx.x;
    const int tx  = t & 15, ty = t >> 4;
    const int tx4 = tx * 4, ty4 = ty * 4;
    const int am  = t >> 2, ak4 = (t & 3) * 4;
    const int xk  = ty,     xn4 = tx4;

    // inline uvw: u[m] = Wq[m].fsum[b]; wh[d] = Wk[d].gsum[b] + HW*bk[d]
    if (t < 64) {
        const float* wrow = Wq + (long)(m0 + t) * C_;
        const float* s = fsum + b * C_;
        float a = 0.0f;
        for (int e2 = 0; e2 < C_; ++e2) a = fmaf(wrow[e2], s[e2], a);
        u_s[t] = a;
    } else if (t < 128) {
        const int d = n0 + (t - 64);
        const float* wrow = Wk + (long)d * C_;
        const float* s = gsum + b * C_;
        float a = 0.0f;
        for (int e2 = 0; e2 < C_; ++e2) a = fmaf(wrow[e2], s[e2], a);
        wh_s[t - 64] = a + (float)HW_ * bk[d];
    }

    float acc[4][4] = {};
    for (int k0 = 0; k0 < C_; k0 += BK64) {
        float4 av = *reinterpret_cast<const float4*>(&Wq[(long)(m0 + am) * C_ + k0 + ak4]);
        float4 xv = *reinterpret_cast<const float4*>(&Tb[(long)(k0 + xk) * C_ + n0 + xn4]);
        As[ak4+0][am]=av.x; As[ak4+1][am]=av.y; As[ak4+2][am]=av.z; As[ak4+3][am]=av.w;
        *reinterpret_cast<float4*>(&Bs[xk][xn4]) = xv;
        __syncthreads();
        #pragma unroll
        for (int kk = 0; kk < BK64; ++kk) {
            float4 a = *reinterpret_cast<const float4*>(&As[kk][ty4]);
            float4 x = *reinterpret_cast<const float4*>(&Bs[kk][tx4]);
            const float ar[4] = {a.x,a.y,a.z,a.w};
            const float xr[4] = {x.x,x.y,x.z,x.w};
            #pragma unroll
            for (int r = 0; r < 4; ++r)
                #pragma unroll
                for (int s = 0; s < 4; ++s)
                    acc[r][s] = fmaf(ar[r], xr[s], acc[r][s]);
        }
        __syncthreads();
    }

    float4 bkv = *reinterpret_cast<const float4*>(&bk[n0 + tx4]);
    float4 whv = make_float4(wh_s[tx4], wh_s[tx4+1], wh_s[tx4+2], wh_s[tx4+3]);
    #pragma unroll
    for (int r = 0; r < 4; ++r) {
        const int m = m0 + ty4 + r;
        const float um = u_s[ty4 + r];
        const float bm = bq[m];
        float4 o;
        o.x = acc[r][0] + um*bkv.x + bm*whv.x;
        o.y = acc[r][1] + um*bkv.y + bm*whv.y;
        o.z = acc[r][2] + um*bkv.z + bm*whv.z;
        o.w = acc[r][3] + um*bkv.w + bm*whv.w;
        uint h[2], l[2];
        cvt_hl4(o, h, l);
        const long e = (long)b * C_ * C_ + (long)m * C_ + n0 + tx4;
        *reinterpret_cast<uint2*>(&corrh[e]) = make_uint2(h[0], h[1]);
        *reinterpret_cast<uint2*>(&corrl[e]) = make_uint2(l[0], l[1]);
    }
}

// ===========================================================================
extern "C" void kernel_launch(void* const* d_in, const int* in_sizes, int n_in,
                              void* d_out, int out_size, void* d_ws, size_t ws_size,
                              hipStream_t stream)
{
    const float* fg    = (const float*)d_in[0];
    const float* bg    = (const float*)d_in[1];
    const float* mask  = (const float*)d_in[2];
    const float* Wq    = (const float*)d_in[3];
    const float* bq    = (const float*)d_in[4];
    const float* Wk    = (const float*)d_in[5];
    const float* bk    = (const float*)d_in[6];
    const float* Wv    = (const float*)d_in[7];
    const float* bv    = (const float*)d_in[8];
    const float* gamma = (const float*)d_in[9];
    float* out = (float*)d_out;

    // ---- workspace layout (bytes) ----
    char* ws = (char*)d_ws;
    float*  part   = (float*)(ws);                        // 33,554,432
    float*  S1     = (float*)(ws + 33554432);             // 2,097,152
    float*  T      = (float*)(ws + 35651584);             // 2,097,152
    ushort* corrh  = (ushort*)(ws + 37748736);            // 1,048,576
    ushort* corrl  = (ushort*)(ws + 38797312);            // 1,048,576
    ushort* Wvh    = (ushort*)(ws + 39845888);            // 131,072
    float*  fsum   = (float*)(ws + 39976960);             // 8,192
    float*  gsum   = (float*)(ws + 39985152);             // 8,192
    float*  pmax   = (float*)(ws + 39993344);             // 262,144
    float*  psum   = (float*)(ws + 40255488);             // 262,144

    const dim3 blk(256);

    // 0. zero the atomic accumulators (fsum+gsum contiguous 16 kB)
    hipMemsetAsync(fsum, 0, 16384, stream);

    // 1. Wv -> bf16 hi
    conv_w<<<dim3(64), blk, 0, stream>>>(Wv, Wvh);

    // 2. S1 = F*G^T via split-K MFMA (fused row sums), reduce
    gemm_nt_mfma<<<dim3(2, 2, B_ * KS), blk, 0, stream>>>(fg, bg, part, fsum, gsum);
    reduce_part<<<dim3(B_ * C_ * C_ / 256), blk, 0, stream>>>(part, S1);

    // 3. T = S1 * Wk^T ; corr (bf16 h/l) = Wq*T + u*bk^T + bq*wh^T (uvw inline)
    gemm_nt64<<<dim3(C_ / 64, B_ * C_ / 64), blk, 0, stream>>>(S1, Wk, T);
    gemm_nn64_rank1<<<dim3(4, 4, B_), blk, 0, stream>>>(
        Wq, T, Wk, bk, bq, fsum, gsum, corrh, corrl);

    // 4. stats pass (in-kernel transpose of mask, no S materialization)
    gemm_stats_mfma<<<dim3(HW_ / 128, C_ / 128, B_), blk, 0, stream>>>(
        corrh, corrl, mask, pmax, psum);

    // 5. fused recompute + v-GEMM + finalize (in-kernel transpose of mask/fg)
    gemm_fused_final<<<dim3(HW_ / 128, C_ / 128, B_), blk, 0, stream>>>(
        corrh, corrl, Wvh, mask, fg, pmax, psum, bv, gamma, out);
}